// Round 1
// baseline (1082.535 us; speedup 1.0000x reference)
//
#include <hip/hip_runtime.h>

// Problem constants (from reference)
#define D 128

// One edge is handled by 32 consecutive lanes (half a wave), each lane
// owning a float4 (4 columns). 32 lanes x 16 B = 512 B per edge, fully
// coalesced for the gather read. elu is recomputed per edge (VALU is far
// from the bottleneck; this avoids materializing emb and a second pass).
__global__ void edge_scatter_kernel(const float* __restrict__ ge,
                                    const float* __restrict__ weight,
                                    const int* __restrict__ e_feat,
                                    const int* __restrict__ src,
                                    const int* __restrict__ dst,
                                    float* __restrict__ out,
                                    int n_edges) {
    long long tid = (long long)blockIdx.x * blockDim.x + threadIdx.x;
    int edge = (int)(tid >> 5);
    if (edge >= n_edges) return;
    int col = (int)(tid & 31) * 4;  // column of the first of my 4 floats

    int s = src[edge];
    int d = dst[edge];
    int e = e_feat[edge];
    float mult = (e == 0 || e == 6 || e == 14 || e == 30) ? 2.0f : 1.0f;

    const float4 w = *reinterpret_cast<const float4*>(weight + col);
    const float4 g = *reinterpret_cast<const float4*>(ge + (long long)s * D + col);

    float4 v;
    v.x = g.x * w.x;
    v.y = g.y * w.y;
    v.z = g.z * w.z;
    v.w = g.w * w.w;
    // elu
    v.x = (v.x > 0.0f) ? v.x : (expf(v.x) - 1.0f);
    v.y = (v.y > 0.0f) ? v.y : (expf(v.y) - 1.0f);
    v.z = (v.z > 0.0f) ? v.z : (expf(v.z) - 1.0f);
    v.w = (v.w > 0.0f) ? v.w : (expf(v.w) - 1.0f);

    float* o = out + (long long)d * D + col;
    atomicAdd(o + 0, v.x * mult);
    atomicAdd(o + 1, v.y * mult);
    atomicAdd(o + 2, v.z * mult);
    atomicAdd(o + 3, v.w * mult);
}

extern "C" void kernel_launch(void* const* d_in, const int* in_sizes, int n_in,
                              void* d_out, int out_size, void* d_ws, size_t ws_size,
                              hipStream_t stream) {
    const float* ge     = (const float*)d_in[0];   // [N, 128]
    const float* weight = (const float*)d_in[1];   // [1, 128]
    const int*   e_feat = (const int*)d_in[2];     // [E]
    const int*   src    = (const int*)d_in[3];     // [E]
    const int*   dst    = (const int*)d_in[4];     // [E]
    float* out = (float*)d_out;                    // [N, 128]

    int n_edges = in_sizes[2];

    // Output is poisoned (0xAA) before timing and never re-poisoned between
    // replays -> zero it at the start of every call (deterministic).
    hipMemsetAsync(d_out, 0, (size_t)out_size * sizeof(float), stream);

    long long total_threads = (long long)n_edges * 32;
    int block = 256;
    int grid = (int)((total_threads + block - 1) / block);
    edge_scatter_kernel<<<grid, block, 0, stream>>>(ge, weight, e_feat, src, dst,
                                                    out, n_edges);
}

// Round 2
// 134.439 us; speedup vs baseline: 8.0523x; 8.0523x over previous
//
#include <hip/hip_runtime.h>

#define D 128

// ---------------------------------------------------------------------------
// Phase 1: histogram of dst
// ---------------------------------------------------------------------------
__global__ void hist_kernel(const int* __restrict__ dst, int* __restrict__ counts,
                            int n_edges) {
    int i = blockIdx.x * blockDim.x + threadIdx.x;
    if (i < n_edges) atomicAdd(&counts[dst[i]], 1);
}

// ---------------------------------------------------------------------------
// Phase 2a: per-chunk exclusive scan (256 elems/block) + block totals
// ---------------------------------------------------------------------------
__global__ void scan1_kernel(const int* __restrict__ counts, int* __restrict__ offsets,
                             int* __restrict__ bsum, int n_nodes) {
    __shared__ int s[256];
    int t = threadIdx.x;
    int idx = blockIdx.x * 256 + t;
    int v = (idx < n_nodes) ? counts[idx] : 0;
    s[t] = v;
    __syncthreads();
    // Hillis-Steele inclusive scan over 256
    for (int d = 1; d < 256; d <<= 1) {
        int x = (t >= d) ? s[t - d] : 0;
        __syncthreads();
        s[t] += x;
        __syncthreads();
    }
    if (idx < n_nodes) offsets[idx] = s[t] - v;  // exclusive, chunk-local
    if (t == 255) bsum[blockIdx.x] = s[t];       // chunk total
}

// ---------------------------------------------------------------------------
// Phase 2b: exclusive scan of the (<=256) block totals, single block
// ---------------------------------------------------------------------------
__global__ void scan2_kernel(int* __restrict__ bsum, int nchunks) {
    __shared__ int s[256];
    int t = threadIdx.x;
    int v = (t < nchunks) ? bsum[t] : 0;
    s[t] = v;
    __syncthreads();
    for (int d = 1; d < 256; d <<= 1) {
        int x = (t >= d) ? s[t - d] : 0;
        __syncthreads();
        s[t] += x;
        __syncthreads();
    }
    if (t < nchunks) bsum[t] = s[t] - v;  // exclusive
}

// ---------------------------------------------------------------------------
// Phase 2c: add block offsets; also init cursor = offsets and offsets[N] = E
// ---------------------------------------------------------------------------
__global__ void scan3_kernel(int* __restrict__ offsets, int* __restrict__ cursor,
                             const int* __restrict__ bsum, int n_nodes, int n_edges) {
    int idx = blockIdx.x * 256 + threadIdx.x;
    if (idx < n_nodes) {
        int off = offsets[idx] + bsum[blockIdx.x];
        offsets[idx] = off;
        cursor[idx] = off;
    }
    if (idx == 0) offsets[n_nodes] = n_edges;  // every dst < n_nodes -> total == E
}

// ---------------------------------------------------------------------------
// Phase 3: scatter edge records into dst-sorted buckets.
// Record: src index (31 bits) | type-match flag (bit 31).
// ---------------------------------------------------------------------------
__global__ void fill_kernel(const int* __restrict__ e_feat, const int* __restrict__ src,
                            const int* __restrict__ dst, int* __restrict__ cursor,
                            unsigned int* __restrict__ bucket, int n_edges) {
    int i = blockIdx.x * blockDim.x + threadIdx.x;
    if (i >= n_edges) return;
    int e = e_feat[i];
    unsigned int flag = (e == 0 || e == 6 || e == 14 || e == 30) ? 1u : 0u;
    int pos = atomicAdd(&cursor[dst[i]], 1);
    bucket[pos] = (unsigned int)src[i] | (flag << 31);
}

// ---------------------------------------------------------------------------
// Phase 4: per-node register accumulation. 32 lanes per node, float4 per lane.
// No atomics; one coalesced 512 B store per node.
// ---------------------------------------------------------------------------
__global__ void gather_kernel(const float* __restrict__ ge,
                              const float* __restrict__ weight,
                              const int* __restrict__ offsets,
                              const unsigned int* __restrict__ bucket,
                              float* __restrict__ out, int n_nodes) {
    long long tid = (long long)blockIdx.x * blockDim.x + threadIdx.x;
    int node = (int)(tid >> 5);
    if (node >= n_nodes) return;
    int col = (int)(tid & 31) * 4;

    const float4 w = *reinterpret_cast<const float4*>(weight + col);
    float4 acc = make_float4(0.f, 0.f, 0.f, 0.f);

    int beg = offsets[node];
    int end = offsets[node + 1];
    for (int i = beg; i < end; ++i) {
        unsigned int rec = bucket[i];  // same addr for all 32 lanes -> broadcast
        int s = (int)(rec & 0x7FFFFFFFu);
        float mult = (rec >> 31) ? 2.0f : 1.0f;

        const float4 g = *reinterpret_cast<const float4*>(ge + (long long)s * D + col);
        float4 v;
        v.x = g.x * w.x; v.y = g.y * w.y; v.z = g.z * w.z; v.w = g.w * w.w;
        v.x = (v.x > 0.0f) ? v.x : (__expf(v.x) - 1.0f);
        v.y = (v.y > 0.0f) ? v.y : (__expf(v.y) - 1.0f);
        v.z = (v.z > 0.0f) ? v.z : (__expf(v.z) - 1.0f);
        v.w = (v.w > 0.0f) ? v.w : (__expf(v.w) - 1.0f);
        acc.x += v.x * mult; acc.y += v.y * mult;
        acc.z += v.z * mult; acc.w += v.w * mult;
    }

    *reinterpret_cast<float4*>(out + (long long)node * D + col) = acc;
}

extern "C" void kernel_launch(void* const* d_in, const int* in_sizes, int n_in,
                              void* d_out, int out_size, void* d_ws, size_t ws_size,
                              hipStream_t stream) {
    const float* ge     = (const float*)d_in[0];   // [N, 128]
    const float* weight = (const float*)d_in[1];   // [1, 128]
    const int*   e_feat = (const int*)d_in[2];     // [E]
    const int*   src    = (const int*)d_in[3];     // [E]
    const int*   dst    = (const int*)d_in[4];     // [E]
    float* out = (float*)d_out;                    // [N, 128]

    int n_edges = in_sizes[2];
    int n_nodes = out_size / D;

    // Workspace layout (256 B aligned slabs): counts | offsets | cursor | bsum | bucket
    char* ws = (char*)d_ws;
    size_t o0 = 0;
    size_t o1 = o0 + (((size_t)n_nodes * 4 + 255) & ~(size_t)255);        // counts
    size_t o2 = o1 + (((size_t)(n_nodes + 1) * 4 + 255) & ~(size_t)255);  // offsets
    size_t o3 = o2 + (((size_t)n_nodes * 4 + 255) & ~(size_t)255);        // cursor
    size_t o4 = o3 + 1024;                                                // bsum
    int*          counts  = (int*)(ws + o0);
    int*          offsets = (int*)(ws + o1);
    int*          cursor  = (int*)(ws + o2);
    int*          bsum    = (int*)(ws + o3);
    unsigned int* bucket  = (unsigned int*)(ws + o4);

    int nchunks = (n_nodes + 255) / 256;  // 196 for N=50000 (fits single-block scan2)

    hipMemsetAsync(counts, 0, (size_t)n_nodes * 4, stream);

    int eb = (n_edges + 255) / 256;
    hist_kernel<<<eb, 256, 0, stream>>>(dst, counts, n_edges);
    scan1_kernel<<<nchunks, 256, 0, stream>>>(counts, offsets, bsum, n_nodes);
    scan2_kernel<<<1, 256, 0, stream>>>(bsum, nchunks);
    scan3_kernel<<<nchunks, 256, 0, stream>>>(offsets, cursor, bsum, n_nodes, n_edges);
    fill_kernel<<<eb, 256, 0, stream>>>(e_feat, src, dst, cursor, bucket, n_edges);

    long long total_threads = (long long)n_nodes * 32;
    int gb = (int)((total_threads + 255) / 256);
    gather_kernel<<<gb, 256, 0, stream>>>(ge, weight, offsets, bucket, out, n_nodes);
}